// Round 1
// baseline (503.854 us; speedup 1.0000x reference)
//
#include <hip/hip_runtime.h>

// ---------------------------------------------------------------------------
// EdgeNetwork: out[e] = tanh(relu(cat(h[dst[e]], h[src[e]], dR[e]) @ W1 + b1) @ W2 + b2)
// E=640000, F=128, MID=192, OUT=128.  bf16 MFMA (16x16x32), fp32 accumulate.
// v2: h pre-converted to bf16 (halves gather bytes, kills f2bf in hot loop),
//     staging via global_load_lds w/ source-side XOR swizzle (linear LDS dest),
//     nontemporal output stores (keep h L2/L3-resident), 5 blocks/CU (LDS=32KB).
// ---------------------------------------------------------------------------

#define F_IN   128
#define MID    192
#define OUT_N  128
#define K1     256          // 2*F (dR column handled as rank-1 epilogue)
#define M_TILE 64           // edges per block
#define H_STRIDE 200        // bf16 elements; 400 B -> 100 dwords == 4 mod 32 banks

typedef __attribute__((ext_vector_type(8))) short bf16x8;            // 8 bf16 = 4 VGPRs
typedef __attribute__((ext_vector_type(8))) unsigned short u16x8;
typedef __attribute__((ext_vector_type(4))) float f32x4;

__device__ __forceinline__ unsigned short f2bf(float f) {
    unsigned u = __builtin_bit_cast(unsigned, f);
    u = (u + 0x7FFFu + ((u >> 16) & 1u)) >> 16;   // round-to-nearest-even
    return (unsigned short)u;
}

// Pack W1 (rows 0..255) and W2 into bf16, B-fragment-major:
//   p[(ktile*N + n)*32 + kin], k = ktile*32 + kin.
// Also copy W1 row 256 (dR weights) as fp32.
__global__ void pack_weights(const float* __restrict__ W1,
                             const float* __restrict__ W2,
                             unsigned short* __restrict__ p1,
                             unsigned short* __restrict__ p2,
                             float* __restrict__ wdr) {
    int i = blockIdx.x * 256 + threadIdx.x;
    if (i < K1 * MID) {              // 49152
        int kin = i & 31;
        int rest = i >> 5;
        int n = rest % MID;
        int kt = rest / MID;
        p1[i] = f2bf(W1[(kt * 32 + kin) * MID + n]);
    }
    int j = i - K1 * MID;
    if (j >= 0 && j < MID * OUT_N) { // 24576
        int kin = j & 31;
        int rest = j >> 5;
        int n = rest & 127;
        int kt = rest >> 7;
        p2[j] = f2bf(W2[(kt * 32 + kin) * OUT_N + n]);
    }
    if (i < MID) wdr[i] = W1[256 * MID + i];
}

// h (fp32) -> hb (bf16), 8 elements/thread
__global__ void hconv(const float* __restrict__ h,
                      unsigned short* __restrict__ hb, int n8) {
    int i = blockIdx.x * 256 + threadIdx.x;
    if (i >= n8) return;
    const float4* hp = (const float4*)h;
    float4 v0 = hp[2 * i];
    float4 v1 = hp[2 * i + 1];
    u16x8 o;
    o[0] = f2bf(v0.x); o[1] = f2bf(v0.y); o[2] = f2bf(v0.z); o[3] = f2bf(v0.w);
    o[4] = f2bf(v1.x); o[5] = f2bf(v1.y); o[6] = f2bf(v1.z); o[7] = f2bf(v1.w);
    *((u16x8*)hb + i) = o;
}

__global__ __launch_bounds__(256, 5)
void edge_mlp_kernel(const unsigned short* __restrict__ hb,
                     const float* __restrict__ dR,
                     const int*   __restrict__ src_idx,
                     const int*   __restrict__ dst_idx,
                     const float* __restrict__ b1,
                     const float* __restrict__ b2,
                     const unsigned short* __restrict__ p1,
                     const unsigned short* __restrict__ p2,
                     const float* __restrict__ wdr,
                     float* __restrict__ out) {
    // A tile: 64 edges x 256 bf16 (dst row | src row), linear 512 B/edge.
    // 16B chunk c of edge e holds GLOBAL chunk c ^ (e&7)  (source-side swizzle,
    // required because global_load_lds dest is wave-uniform base + lane*16).
    __shared__ __align__(16) unsigned short sA[M_TILE * 256];   // 32768 B exactly -> 5 blocks/CU

    const int tid  = threadIdx.x;
    const int lane = tid & 63;
    const int w    = tid >> 6;          // wave 0..3
    const int e0   = blockIdx.x * M_TILE;

    const float dr_own = dR[e0 + lane]; // lane L holds dR[e0+L]; shuffled later

    // ---- stage A tile via global_load_lds (1 instr = 1024 B = 2 edge-halves x 2) ----
    {
        const int g = lane >> 4;        // 0..3: {e dst, e src, e+1 dst, e+1 src}
        const int c = lane & 15;        // 16B chunk within a 256B row
        const int part = g & 1;
        const int* __restrict__ ip = part ? src_idx : dst_idx;
        const int eb = w * 16 + (g >> 1);
        int rows[8];
#pragma unroll
        for (int i = 0; i < 8; ++i) rows[i] = ip[e0 + eb + 2 * i];
#pragma unroll
        for (int i = 0; i < 8; ++i) {
            const int el = eb + 2 * i;                     // edge this lane serves
            const unsigned short* gp =
                hb + ((size_t)rows[i] << 7) + ((c ^ (el & 7)) << 3);
            unsigned short* lp = &sA[(w * 16 + 2 * i) * 256];  // wave-uniform
            __builtin_amdgcn_global_load_lds(
                (const __attribute__((address_space(1))) void*)gp,
                (__attribute__((address_space(3))) void*)lp,
                16, 0, 0);
        }
    }
    __syncthreads();

    const int l15 = lane & 15;
    const int q   = lane >> 4;

    // ---- layer 1: hid[64][192] = relu(A @ W1 + b1 + dR*wdr) ----
    // wave w owns n-tiles {w, w+4, w+8}; m-subtiles 0..3
    f32x4 acc1[4][3] = {};
    for (int kt = 0; kt < 8; ++kt) {
        bf16x8 a[4];
#pragma unroll
        for (int m = 0; m < 4; ++m) {
            const int r = m * 16 + l15;
            // logical chunk kt*4+q, un-swizzle with ^ (r&7) (involution)
            a[m] = *(const bf16x8*)(&sA[r * 256 + (((kt * 4 + q) ^ (r & 7)) << 3)]);
        }
#pragma unroll
        for (int ni = 0; ni < 3; ++ni) {
            const int nb = (w + ni * 4) * 16 + l15;
            bf16x8 bf = *(const bf16x8*)(&p1[((kt * MID + nb) << 5) + (q << 3)]);
#pragma unroll
            for (int m = 0; m < 4; ++m)
                acc1[m][ni] = __builtin_amdgcn_mfma_f32_16x16x32_bf16(a[m], bf, acc1[m][ni], 0, 0, 0);
        }
    }
    __syncthreads();   // everyone done reading sA before hid overwrites it

    // dR values needed in epilogue 1: e = m*16 + q*4 + r  (16 per thread)
    float drv[16];
#pragma unroll
    for (int m = 0; m < 4; ++m)
#pragma unroll
        for (int r = 0; r < 4; ++r)
            drv[m * 4 + r] = __shfl(dr_own, m * 16 + q * 4 + r);

    // ---- epilogue 1 -> hid (bf16) in LDS, aliasing sA ----
    unsigned short* sH = sA;
#pragma unroll
    for (int ni = 0; ni < 3; ++ni) {
        const int n = (w + ni * 4) * 16 + l15;
        const float bb = b1[n];
        const float wd = wdr[n];
#pragma unroll
        for (int m = 0; m < 4; ++m) {
#pragma unroll
            for (int r = 0; r < 4; ++r) {
                const int e = m * 16 + q * 4 + r;
                float v = acc1[m][ni][r] + bb + drv[m * 4 + r] * wd;
                v = fmaxf(v, 0.0f);
                sH[e * H_STRIDE + n] = f2bf(v);
            }
        }
    }
    __syncthreads();

    // ---- layer 2: out = tanh(hid @ W2 + b2); wave w owns n-tiles {w, w+4} ----
    f32x4 acc2[4][2] = {};
    for (int kt = 0; kt < 6; ++kt) {
        bf16x8 a[4];
#pragma unroll
        for (int m = 0; m < 4; ++m)
            a[m] = *(const bf16x8*)(&sH[(m * 16 + l15) * H_STRIDE + kt * 32 + q * 8]);
#pragma unroll
        for (int ni = 0; ni < 2; ++ni) {
            const int nb = (w + ni * 4) * 16 + l15;
            bf16x8 bf = *(const bf16x8*)(&p2[((kt * OUT_N + nb) << 5) + (q << 3)]);
#pragma unroll
            for (int m = 0; m < 4; ++m)
                acc2[m][ni] = __builtin_amdgcn_mfma_f32_16x16x32_bf16(a[m], bf, acc2[m][ni], 0, 0, 0);
        }
    }

    // ---- epilogue 2: tanh + nontemporal fp32 store (don't thrash L2/L3) ----
#pragma unroll
    for (int ni = 0; ni < 2; ++ni) {
        const int n = (w + ni * 4) * 16 + l15;
        const float bb = b2[n];
#pragma unroll
        for (int m = 0; m < 4; ++m) {
#pragma unroll
            for (int r = 0; r < 4; ++r) {
                const int e = e0 + m * 16 + q * 4 + r;
                float x = acc2[m][ni][r] + bb;
                x = fminf(fmaxf(x, -10.0f), 10.0f);
                float t = __expf(2.0f * x);               // tanh = (e^2x - 1)/(e^2x + 1)
                float y = (t - 1.0f) * __builtin_amdgcn_rcpf(t + 1.0f);
                __builtin_nontemporal_store(y, &out[(size_t)e * OUT_N + n]);
            }
        }
    }
}

extern "C" void kernel_launch(void* const* d_in, const int* in_sizes, int n_in,
                              void* d_out, int out_size, void* d_ws, size_t ws_size,
                              hipStream_t stream) {
    const float* h   = (const float*)d_in[0];
    const float* dR  = (const float*)d_in[1];
    const int* src   = (const int*)d_in[2];
    const int* dst   = (const int*)d_in[3];
    const float* W1  = (const float*)d_in[4];
    const float* b1  = (const float*)d_in[5];
    const float* W2  = (const float*)d_in[6];
    const float* b2  = (const float*)d_in[7];
    float* out       = (float*)d_out;

    const int hn = in_sizes[0];   // n_nodes * 128 elements
    const int E  = in_sizes[1];

    // workspace layout: hb (hn bf16) | p1 | p2 | wdr   (~25.75 MB total)
    unsigned short* hbuf = (unsigned short*)d_ws;
    unsigned short* p1   = hbuf + hn;                    // 25.6e6 B offset, 16B aligned
    unsigned short* p2   = p1 + K1 * MID;
    float* wdr           = (float*)(p2 + MID * OUT_N);

    hconv<<<(hn / 8 + 255) / 256, 256, 0, stream>>>(h, hbuf, hn / 8);
    pack_weights<<<(K1 * MID + MID * OUT_N + 255) / 256, 256, 0, stream>>>(W1, W2, p1, p2, wdr);
    edge_mlp_kernel<<<E / M_TILE, 256, 0, stream>>>(hbuf, dR, src, dst, b1, b2, p1, p2, wdr, out);
}

// Round 2
// 503.441 us; speedup vs baseline: 1.0008x; 1.0008x over previous
//
#include <hip/hip_runtime.h>

// ---------------------------------------------------------------------------
// EdgeNetwork: out[e] = tanh(relu(cat(h[dst[e]], h[src[e]], dR[e]) @ W1 + b1) @ W2 + b2)
// E=640000, F=128, MID=192, OUT=128.  bf16 MFMA (16x16x32), fp32 accumulate.
// v3: persistent 2-phase pipelined blocks (T3-lite):
//   - 512 persistent blocks (2/CU), grid-stride over 10000 edge-tiles
//   - double-buffered A tile (2 x 32KB LDS = 64KB exactly -> 2 blocks/CU)
//   - per tile: issue gathers(t+1) -> prefetch idx(t+2) -> raw s_barrier ->
//     compute tile t.  Gathers get a full iteration to land (latency hidden).
//     Stage-complete guarantee is the compiler's own FIFO vmcnt wait on the
//     index registers (loaded AFTER the previous stage issue), so no
//     hand-counted vmcnt is needed; raw barriers avoid the vmcnt(0) drain
//     __syncthreads would insert (the m97-ceiling mechanism).
//   - W1/W2 fragments persistent in registers (144 VGPR) -> zero weight
//     traffic in the hot loop
//   - plain stores (v2's nontemporal stores inflated WRITE_SIZE 1.45x)
// ---------------------------------------------------------------------------

#define F_IN   128
#define MID    192
#define OUT_N  128
#define K1     256          // 2*F (dR column handled as rank-1 epilogue)
#define M_TILE 64           // edges per tile
#define H_STRIDE 200        // bf16 elements; 400 B -> 100 dwords == 4 mod 32 banks
#define NBLK   512          // persistent grid: 2 blocks/CU

typedef __attribute__((ext_vector_type(8))) short bf16x8;            // 8 bf16 = 4 VGPRs
typedef __attribute__((ext_vector_type(8))) unsigned short u16x8;
typedef __attribute__((ext_vector_type(4))) float f32x4;

__device__ __forceinline__ unsigned short f2bf(float f) {
    unsigned u = __builtin_bit_cast(unsigned, f);
    u = (u + 0x7FFFu + ((u >> 16) & 1u)) >> 16;   // round-to-nearest-even
    return (unsigned short)u;
}

// Pack W1 (rows 0..255) and W2 into bf16, B-fragment-major:
//   p[(ktile*N + n)*32 + kin], k = ktile*32 + kin.
// Also copy W1 row 256 (dR weights) as fp32.
__global__ void pack_weights(const float* __restrict__ W1,
                             const float* __restrict__ W2,
                             unsigned short* __restrict__ p1,
                             unsigned short* __restrict__ p2,
                             float* __restrict__ wdr) {
    int i = blockIdx.x * 256 + threadIdx.x;
    if (i < K1 * MID) {              // 49152
        int kin = i & 31;
        int rest = i >> 5;
        int n = rest % MID;
        int kt = rest / MID;
        p1[i] = f2bf(W1[(kt * 32 + kin) * MID + n]);
    }
    int j = i - K1 * MID;
    if (j >= 0 && j < MID * OUT_N) { // 24576
        int kin = j & 31;
        int rest = j >> 5;
        int n = rest & 127;
        int kt = rest >> 7;
        p2[j] = f2bf(W2[(kt * 32 + kin) * OUT_N + n]);
    }
    if (i < MID) wdr[i] = W1[256 * MID + i];
}

// h (fp32) -> hb (bf16), 8 elements/thread
__global__ void hconv(const float* __restrict__ h,
                      unsigned short* __restrict__ hb, int n8) {
    int i = blockIdx.x * 256 + threadIdx.x;
    if (i >= n8) return;
    const float4* hp = (const float4*)h;
    float4 v0 = hp[2 * i];
    float4 v1 = hp[2 * i + 1];
    u16x8 o;
    o[0] = f2bf(v0.x); o[1] = f2bf(v0.y); o[2] = f2bf(v0.z); o[3] = f2bf(v0.w);
    o[4] = f2bf(v1.x); o[5] = f2bf(v1.y); o[6] = f2bf(v1.z); o[7] = f2bf(v1.w);
    *((u16x8*)hb + i) = o;
}

#define SBAR()  do { __builtin_amdgcn_sched_barrier(0); \
                     __builtin_amdgcn_s_barrier();      \
                     __builtin_amdgcn_sched_barrier(0); } while (0)

__global__ __launch_bounds__(256, 2)
void edge_mlp_kernel(const unsigned short* __restrict__ hb,
                     const float* __restrict__ dR,
                     const int*   __restrict__ src_idx,
                     const int*   __restrict__ dst_idx,
                     const float* __restrict__ b1,
                     const float* __restrict__ b2,
                     const unsigned short* __restrict__ p1,
                     const unsigned short* __restrict__ p2,
                     const float* __restrict__ wdr,
                     float* __restrict__ out,
                     int NT) {
    // A tile: 64 edges x 256 bf16 (dst row | src row), linear 512 B/edge.
    // 16B chunk c of edge e holds GLOBAL chunk c ^ (e&7) (source-side swizzle:
    // global_load_lds dest is wave-uniform base + lane*16, so LDS stays linear).
    __shared__ __align__(16) unsigned short sA[2][M_TILE * 256];   // 65536 B -> 2 blocks/CU

    const int tid  = threadIdx.x;
    const int lane = tid & 63;
    const int w    = tid >> 6;          // wave 0..3
    const int l15  = lane & 15;
    const int q    = lane >> 4;

    // staging geometry: g selects {e dst, e src, e+1 dst, e+1 src}; c = 16B chunk
    const int g    = lane >> 4;
    const int c    = lane & 15;
    const int part = g & 1;
    const int* __restrict__ ip = part ? src_idx : dst_idx;
    const int eb   = w * 16 + (g >> 1);

    // ---- persistent weight fragments (loaded once, reused ~20 tiles) ----
    bf16x8 w1f[8][3];                   // 96 VGPR
#pragma unroll
    for (int kt = 0; kt < 8; ++kt)
#pragma unroll
        for (int ni = 0; ni < 3; ++ni) {
            const int nb = (w + ni * 4) * 16 + l15;
            w1f[kt][ni] = *(const bf16x8*)(&p1[((kt * MID + nb) << 5) + (q << 3)]);
        }
    bf16x8 w2f[6][2];                   // 48 VGPR
#pragma unroll
    for (int kt = 0; kt < 6; ++kt)
#pragma unroll
        for (int ni = 0; ni < 2; ++ni) {
            const int nb = (w + ni * 4) * 16 + l15;
            w2f[kt][ni] = *(const bf16x8*)(&p2[((kt * OUT_N + nb) << 5) + (q << 3)]);
        }
    float bb1[3], wd1[3], bb2[2];
#pragma unroll
    for (int ni = 0; ni < 3; ++ni) {
        const int n = (w + ni * 4) * 16 + l15;
        bb1[ni] = b1[n]; wd1[ni] = wdr[n];
    }
#pragma unroll
    for (int ni = 0; ni < 2; ++ni) bb2[ni] = b2[(w + ni * 4) * 16 + l15];

    const int t0 = blockIdx.x;
    if (t0 >= NT) return;

    // ---- prologue: stage tile t0 into buf 0; prefetch idx/dR of t0+NBLK ----
    int idxc[8];                        // indices for the NEXT tile to stage
    {
        const int base = t0 * M_TILE + eb;
#pragma unroll
        for (int i = 0; i < 8; ++i) idxc[i] = ip[base + 2 * i];
#pragma unroll
        for (int i = 0; i < 8; ++i) {
            const int el = eb + 2 * i;
            const unsigned short* gp =
                hb + ((size_t)idxc[i] << 7) + ((c ^ (el & 7)) << 3);
            unsigned short* lp = &sA[0][(w * 16 + 2 * i) * 256];
            __builtin_amdgcn_global_load_lds(
                (const __attribute__((address_space(1))) void*)gp,
                (__attribute__((address_space(3))) void*)lp, 16, 0, 0);
        }
    }
    int t1 = t0 + NBLK; if (t1 > NT - 1) t1 = NT - 1;   // clamped (always valid)
    {
        const int base = t1 * M_TILE + eb;
#pragma unroll
        for (int i = 0; i < 8; ++i) idxc[i] = ip[base + 2 * i];
    }
    float dr_now = dR[t0 * M_TILE + lane];
    float dr_nxt = dR[t1 * M_TILE + lane];

    int cur = 0;
    for (int t = t0; t < NT; t += NBLK, cur ^= 1) {
        // ---- 1. issue gathers for next tile (clamped: uniform control flow,
        //         and the idx-reg vmcnt dependency provably retires stage(t)) ----
#pragma unroll
        for (int i = 0; i < 8; ++i) {
            const int el = eb + 2 * i;
            const unsigned short* gp =
                hb + ((size_t)idxc[i] << 7) + ((c ^ (el & 7)) << 3);
            unsigned short* lp = &sA[cur ^ 1][(w * 16 + 2 * i) * 256];
            __builtin_amdgcn_global_load_lds(
                (const __attribute__((address_space(1))) void*)gp,
                (__attribute__((address_space(3))) void*)lp, 16, 0, 0);
        }
        // ---- 2. prefetch idx for t+2*NBLK (lands during this iteration) ----
        {
            int t2 = t + 2 * NBLK; if (t2 > NT - 1) t2 = NT - 1;
            const int base = t2 * M_TILE + eb;
#pragma unroll
            for (int i = 0; i < 8; ++i) idxc[i] = ip[base + 2 * i];
        }
        // ---- 3. B1: stage(t) visible to all waves (own drained via idx dep) ----
        SBAR();

        // ---- 4. layer 1: hid = relu(A @ W1 + b1 + dR*wdr) ----
        const unsigned short* sAc = &sA[cur][0];
        f32x4 acc1[4][3] = {};
#pragma unroll
        for (int kt = 0; kt < 8; ++kt) {
            bf16x8 a[4];
#pragma unroll
            for (int m = 0; m < 4; ++m) {
                const int r = m * 16 + l15;
                a[m] = *(const bf16x8*)(&sAc[r * 256 + (((kt * 4 + q) ^ (r & 7)) << 3)]);
            }
#pragma unroll
            for (int ni = 0; ni < 3; ++ni)
#pragma unroll
                for (int m = 0; m < 4; ++m)
                    acc1[m][ni] = __builtin_amdgcn_mfma_f32_16x16x32_bf16(
                        a[m], w1f[kt][ni], acc1[m][ni], 0, 0, 0);
        }
        // ---- B2: all waves done reading A before hid overwrites it ----
        SBAR();

        // dR values for this tile's 16 edge-rows per thread
        float drv[16];
#pragma unroll
        for (int m = 0; m < 4; ++m)
#pragma unroll
            for (int r = 0; r < 4; ++r)
                drv[m * 4 + r] = __shfl(dr_now, m * 16 + q * 4 + r);

        // ---- epilogue 1 -> hid (bf16) in LDS, aliasing sA[cur] ----
        unsigned short* sH = &sA[cur][0];
#pragma unroll
        for (int ni = 0; ni < 3; ++ni) {
            const int n = (w + ni * 4) * 16 + l15;
#pragma unroll
            for (int m = 0; m < 4; ++m)
#pragma unroll
                for (int r = 0; r < 4; ++r) {
                    const int e = m * 16 + q * 4 + r;
                    float v = acc1[m][ni][r] + bb1[ni] + drv[m * 4 + r] * wd1[ni];
                    v = fmaxf(v, 0.0f);
                    sH[e * H_STRIDE + n] = f2bf(v);
                }
        }
        asm volatile("s_waitcnt lgkmcnt(0)" ::: "memory");
        // ---- B3: hid visible before layer-2 reads ----
        SBAR();

        // ---- layer 2: out = tanh(hid @ W2 + b2) ----
        f32x4 acc2[4][2] = {};
#pragma unroll
        for (int kt = 0; kt < 6; ++kt) {
            bf16x8 a[4];
#pragma unroll
            for (int m = 0; m < 4; ++m)
                a[m] = *(const bf16x8*)(&sH[(m * 16 + l15) * H_STRIDE + kt * 32 + q * 8]);
#pragma unroll
            for (int ni = 0; ni < 2; ++ni)
#pragma unroll
                for (int m = 0; m < 4; ++m)
                    acc2[m][ni] = __builtin_amdgcn_mfma_f32_16x16x32_bf16(
                        a[m], w2f[kt][ni], acc2[m][ni], 0, 0, 0);
        }
        // ---- B4: all waves done reading sH before next stage overwrites it ----
        SBAR();

        // ---- epilogue 2: tanh + plain fp32 store (registers + global only) ----
#pragma unroll
        for (int ni = 0; ni < 2; ++ni) {
            const int n = (w + ni * 4) * 16 + l15;
#pragma unroll
            for (int m = 0; m < 4; ++m)
#pragma unroll
                for (int r = 0; r < 4; ++r) {
                    const int e = t * M_TILE + m * 16 + q * 4 + r;
                    float x = acc2[m][ni][r] + bb2[ni];
                    x = fminf(fmaxf(x, -10.0f), 10.0f);
                    float tt = __expf(2.0f * x);          // tanh = (e^2x-1)/(e^2x+1)
                    out[(size_t)e * OUT_N + n] = (tt - 1.0f) * __builtin_amdgcn_rcpf(tt + 1.0f);
                }
        }

        // ---- roll dR pipeline: dr for t+NBLK becomes current; fetch t+2*NBLK ----
        dr_now = dr_nxt;
        {
            int t2 = t + 2 * NBLK; if (t2 > NT - 1) t2 = NT - 1;
            dr_nxt = dR[t2 * M_TILE + lane];
        }
    }
}

extern "C" void kernel_launch(void* const* d_in, const int* in_sizes, int n_in,
                              void* d_out, int out_size, void* d_ws, size_t ws_size,
                              hipStream_t stream) {
    const float* h   = (const float*)d_in[0];
    const float* dR  = (const float*)d_in[1];
    const int* src   = (const int*)d_in[2];
    const int* dst   = (const int*)d_in[3];
    const float* W1  = (const float*)d_in[4];
    const float* b1  = (const float*)d_in[5];
    const float* W2  = (const float*)d_in[6];
    const float* b2  = (const float*)d_in[7];
    float* out       = (float*)d_out;

    const int hn = in_sizes[0];   // n_nodes * 128 elements
    const int E  = in_sizes[1];
    const int NT = E / M_TILE;

    // workspace layout: hb (hn bf16) | p1 | p2 | wdr   (~25.75 MB total)
    unsigned short* hbuf = (unsigned short*)d_ws;
    unsigned short* p1   = hbuf + hn;
    unsigned short* p2   = p1 + K1 * MID;
    float* wdr           = (float*)(p2 + MID * OUT_N);

    hconv<<<(hn / 8 + 255) / 256, 256, 0, stream>>>(h, hbuf, hn / 8);
    pack_weights<<<(K1 * MID + MID * OUT_N + 255) / 256, 256, 0, stream>>>(W1, W2, p1, p2, wdr);

    const int grid = NT < NBLK ? NT : NBLK;
    edge_mlp_kernel<<<grid, 256, 0, stream>>>(hbuf, dR, src, dst, b1, b2, p1, p2, wdr, out, NT);
}